// Round 2
// baseline (139.921 us; speedup 1.0000x reference)
//
#include <hip/hip_runtime.h>

#define BQ 32
#define H  128
#define C  512
#define D  128

typedef _Float16 half8v __attribute__((ext_vector_type(8)));
typedef float floatx4 __attribute__((ext_vector_type(4)));

// ---------------------------------------------------------------------------
// scores_kernel: block c (256 thr, 4 waves) -> scores[b][c].
// Identical compute structure to the verified 93.8us r0 kernel (register Q,
// no per-iter barriers -- the r1 LDS/barrier variant regressed +4us).
// CHANGE: qprep_kernel is gone.  Each wave loads its Q fragments directly
// from the fp32 input with the SAME per-lane addressing qprep used, and
// converts to f16 at use.  Q (512 KB fp32) is L2-resident per XCD exactly
// like the old qs buffer was, so the per-iter fetch cost is unchanged; the
// ~48 cvt VALU ops/iter issue on the vector pipe under the ~620cyc of MFMA
// (matrix pipe).  This deletes one kernel launch + one dependency edge.
//
// Q pipeline: 2 fp32 landing slots, prefetch distance 2.
//   iter b: slot s=b&1 holds b's data (landed; loads issued at iter b-2)
//     1. s_waitcnt (compiler RAW) ; cvt slot s -> half8v qc[4]
//     2. reissue slot s with b+2's loads (WAR safe: VALU reads at issue,
//        in-order before the VMEM writes land)
//     3. 16 MFMA on (pa, qc)
// Frag layout (unchanged): B-elem[n=lane&15][k=kb*32+(lane>>4)*8+j],
// s = sh*16+n, i.e. src = q[(b*32 + sh*16+nrow)*H + kb*32 + quad*8 + j].
// ---------------------------------------------------------------------------
__global__ __launch_bounds__(256, 2) void scores_kernel(const float* __restrict__ pos,
                                                        const float* __restrict__ q,
                                                        float* __restrict__ scores) {
  const int c    = blockIdx.x;
  const int tid  = threadIdx.x;
  const int w    = tid >> 6;
  const int lane = tid & 63;
  const int dq   = w & 1;            // d-half
  const int sh   = w >> 1;           // s-half
  const int quad = lane >> 4;
  const int nrow = lane & 15;

  __shared__ float pmm[BQ][4][16];   // [b][wave][s_local]  8 KB

  // Per-lane Q source base (b advances by 32*H floats = 16 KB)
  const float* qsrc = q + ((sh * 16 + nrow) * H + quad * 8);

  // Prime Q slots: b=0 -> slot0, b=1 -> slot1 (issued before P loads so the
  // P-load drain covers their latency too)
  float4 qsl[2][4][2];               // [slot][kb][half]  64 VGPRs
#pragma unroll
  for (int kb = 0; kb < 4; ++kb) {
    qsl[0][kb][0] = *(const float4*)(qsrc + 0 * (BQ * H) + kb * 32);
    qsl[0][kb][1] = *(const float4*)(qsrc + 0 * (BQ * H) + kb * 32 + 4);
  }
#pragma unroll
  for (int kb = 0; kb < 4; ++kb) {
    qsl[1][kb][0] = *(const float4*)(qsrc + 1 * (BQ * H) + kb * 32);
    qsl[1][kb][1] = *(const float4*)(qsrc + 1 * (BQ * H) + kb * 32 + 4);
  }

  // P_c A-frags: A[m = dq*64 + mt*16 + nrow][k = kb*32 + quad*8 + j]
  const float* pc = pos + (size_t)c * (D * H);
  half8v pa[4][4];                   // 64 VGPRs
#pragma unroll
  for (int kb = 0; kb < 4; ++kb)
#pragma unroll
    for (int mt = 0; mt < 4; ++mt) {
      const float* src = pc + ((dq * 64 + mt * 16 + nrow) * H + kb * 32 + quad * 8);
      float4 v0 = *(const float4*)src;
      float4 v1 = *(const float4*)(src + 4);
      half8v f = { (_Float16)v0.x, (_Float16)v0.y, (_Float16)v0.z, (_Float16)v0.w,
                   (_Float16)v1.x, (_Float16)v1.y, (_Float16)v1.z, (_Float16)v1.w };
      pa[mt][kb] = f;
    }

  floatx4 acc[2][4];                 // [buf][mt] (32 VGPRs)
  floatx4 zc = {0.f, 0.f, 0.f, 0.f};

  // C/D: col s_local = lane&15, row d_local = quad*4 + r  [m89/m91]
  auto reduce_store = [&](int b, floatx4 (&a)[4]) {
    float m0 = fmaxf(fmaxf(a[0][0], a[0][1]), fmaxf(a[0][2], a[0][3]));
    float m1 = fmaxf(fmaxf(a[1][0], a[1][1]), fmaxf(a[1][2], a[1][3]));
    float m2 = fmaxf(fmaxf(a[2][0], a[2][1]), fmaxf(a[2][2], a[2][3]));
    float m3 = fmaxf(fmaxf(a[3][0], a[3][1]), fmaxf(a[3][2], a[3][3]));
    float m  = fmaxf(fmaxf(m0, m1), fmaxf(m2, m3));
    m = fmaxf(m, __shfl_xor(m, 16));
    m = fmaxf(m, __shfl_xor(m, 32));
    if (lane < 16) pmm[b][w][lane] = m;
  };

  // main loop: cvt slot (b), reissue slot with b+2, compute b, reduce b-1
#pragma unroll
  for (int b = 0; b < BQ; ++b) {
    const int cur = b & 1;
    const int s   = b & 1;
    half8v qc[4];
#pragma unroll
    for (int kb = 0; kb < 4; ++kb) {
      float4 v0 = qsl[s][kb][0];
      float4 v1 = qsl[s][kb][1];
      half8v f = { (_Float16)v0.x, (_Float16)v0.y, (_Float16)v0.z, (_Float16)v0.w,
                   (_Float16)v1.x, (_Float16)v1.y, (_Float16)v1.z, (_Float16)v1.w };
      qc[kb] = f;
    }
    if (b + 2 < BQ) {
      const float* nb = qsrc + (size_t)(b + 2) * (BQ * H);
#pragma unroll
      for (int kb = 0; kb < 4; ++kb) {
        qsl[s][kb][0] = *(const float4*)(nb + kb * 32);
        qsl[s][kb][1] = *(const float4*)(nb + kb * 32 + 4);
      }
    }
#pragma unroll
    for (int mt = 0; mt < 4; ++mt)
      acc[cur][mt] = __builtin_amdgcn_mfma_f32_16x16x32_f16(pa[mt][0], qc[0], zc, 0, 0, 0);
#pragma unroll
    for (int kb = 1; kb < 4; ++kb)
#pragma unroll
      for (int mt = 0; mt < 4; ++mt)
        acc[cur][mt] = __builtin_amdgcn_mfma_f32_16x16x32_f16(pa[mt][kb], qc[kb], acc[cur][mt], 0, 0, 0);
    if (b > 0) reduce_store(b - 1, acc[cur ^ 1]);
  }
  reduce_store(BQ - 1, acc[1]);   // b=31 landed in acc[1]

  __syncthreads();

  // epilogue: scores[b][c] = 50 * sum_s max over the two d-half waves
  {
    int b  = tid >> 3;
    int t8 = tid & 7;
    float v = 0.f;
#pragma unroll
    for (int j = 0; j < 4; ++j) {
      int s  = t8 * 4 + j;
      int h2 = s >> 4, sl = s & 15;
      v += fmaxf(pmm[b][2 * h2][sl], pmm[b][2 * h2 + 1][sl]);
    }
    v += __shfl_xor(v, 1);
    v += __shfl_xor(v, 2);
    v += __shfl_xor(v, 4);
    if (t8 == 0) scores[b * C + c] = v * 50.0f;   // / TEMPERATURE
  }
}

// ---------------------------------------------------------------------------
// loss_kernel: SINGLE block, 512 thr (8 waves).  Wave w handles b = 4w..4w+3.
// Plain store to out[0] -> no pre-zero of d_out needed (this is what let us
// delete qprep), no atomics.
// ---------------------------------------------------------------------------
__global__ __launch_bounds__(512) void loss_kernel(const float* __restrict__ scores,
                                                   float* __restrict__ out) {
  __shared__ float red[8];
  const int tid = threadIdx.x, w = tid >> 6, lane = tid & 63;
  float part = 0.f;
#pragma unroll
  for (int i = 0; i < 4; ++i) {
    const int b = w * 4 + i;
    const float* row = scores + b * C;
    const float4* r4 = (const float4*)row;
    float4 v0 = r4[lane * 2];
    float4 v1 = r4[lane * 2 + 1];
    float mx = fmaxf(fmaxf(fmaxf(v0.x, v0.y), fmaxf(v0.z, v0.w)),
                     fmaxf(fmaxf(v1.x, v1.y), fmaxf(v1.z, v1.w)));
#pragma unroll
    for (int off = 1; off < 64; off <<= 1) mx = fmaxf(mx, __shfl_xor(mx, off));
    float e = __expf(v0.x - mx) + __expf(v0.y - mx) + __expf(v0.z - mx) + __expf(v0.w - mx)
            + __expf(v1.x - mx) + __expf(v1.y - mx) + __expf(v1.z - mx) + __expf(v1.w - mx);
#pragma unroll
    for (int off = 1; off < 64; off <<= 1) e += __shfl_xor(e, off);
    if (lane == 0) part += mx + __logf(e) - row[0];
  }
  if (lane == 0) red[w] = part;
  __syncthreads();
  if (tid == 0) {
    float s = red[0] + red[1] + red[2] + red[3] + red[4] + red[5] + red[6] + red[7];
    out[0] = s * (1.0f / 32.0f);
  }
}

extern "C" void kernel_launch(void* const* d_in, const int* in_sizes, int n_in,
                              void* d_out, int out_size, void* d_ws, size_t ws_size,
                              hipStream_t stream) {
  const float* q = (const float*)d_in[0];   // [32,32,128] fp32
  const float* p = (const float*)d_in[1];   // [512,128,128] fp32
  float* scores  = (float*)d_ws;            // 64 KB

  scores_kernel<<<C, 256, 0, stream>>>(p, q, scores);
  loss_kernel<<<1, 512, 0, stream>>>(scores, (float*)d_out);
}